// Round 13
// baseline (298.926 us; speedup 1.0000x reference)
//
#include <hip/hip_runtime.h>
#include <cstdint>
#include <cstddef>

static constexpr int NN = 50000;   // nodes
static constexpr int NE = 500000;  // edges
static constexpr int NG = 256;     // graphs

typedef short  frag8  __attribute__((ext_vector_type(8)));   // 8 bf16 (4 VGPRs) MFMA operand
typedef float  f32x4  __attribute__((ext_vector_type(4)));
typedef unsigned short us8 __attribute__((ext_vector_type(8)));
typedef unsigned int   u32x8 __attribute__((ext_vector_type(8)));

__device__ __forceinline__ unsigned short bf16_rne(float f) {
  unsigned u = __builtin_bit_cast(unsigned, f);
  u += 0x7fffu + ((u >> 16) & 1u);
  return (unsigned short)(u >> 16);
}
__device__ __forceinline__ float bf16_to_f(unsigned short h) {
  unsigned u = ((unsigned)h) << 16;
  return __builtin_bit_cast(float, u);
}

// ---------------- W decompose helper: W[K][N] f32 -> WT_hi/lo[Np][Kp] bf16 ----------------
template<int K, int N, int Kp, int Np>
__device__ __forceinline__ void wdec_elem(const float* __restrict__ W,
                                          unsigned short* __restrict__ Wh,
                                          unsigned short* __restrict__ Wl, int idx) {
  if (idx >= Np * Kp) return;
  int n = idx / Kp, k = idx - n * Kp;
  float v = (n < N && k < K) ? W[k * N + n] : 0.f;
  unsigned short h = bf16_rne(v);
  Wh[idx] = h;
  Wl[idx] = bf16_rne(v - bf16_to_f(h));
}

// ---------------- prep mega-kernel: edge count + x-pad + all 7 weight decomps ----------------
static constexpr int PB_COUNT = (NE + 255) / 256;        // 1954
static constexpr int PB_PADX  = (NN * 80) / 256;         // 15625
static constexpr int PB_W1 = (96 * 80) / 256;            // 30
static constexpr int PB_W2 = (96 * 160) / 256;           // 60
static constexpr int PB_W3 = (160 * 320) / 256;          // 200
static constexpr int PB_G1 = (320 * 1024) / 256;         // 1280
static constexpr int PB_G2 = (1024 * 128) / 256;         // 512
static constexpr int PB_F1 = (160 * 1024) / 256;         // 640
static constexpr int PB_F2 = (1024 * 512) / 256;         // 2048
static constexpr int PREP_BLOCKS = PB_COUNT + PB_PADX + PB_W1 + PB_W2 + PB_W3 + PB_G1 + PB_G2 + PB_F1 + PB_F2;

__global__ void k_prep(const int* __restrict__ dst, int* __restrict__ cnt,
                       const float* __restrict__ x, float* __restrict__ x80,
                       const float* __restrict__ W1, unsigned short* wt1H, unsigned short* wt1L,
                       const float* __restrict__ W2, unsigned short* wt2H, unsigned short* wt2L,
                       const float* __restrict__ W3, unsigned short* wt3H, unsigned short* wt3L,
                       const float* __restrict__ Wg1, unsigned short* wg1H, unsigned short* wg1L,
                       const float* __restrict__ Wg2, unsigned short* wg2H, unsigned short* wg2L,
                       const float* __restrict__ Wf1, unsigned short* wf1H, unsigned short* wf1L,
                       const float* __restrict__ Wf2, unsigned short* wf2H, unsigned short* wf2L) {
  int b = blockIdx.x, tid = threadIdx.x;
  if (b < PB_COUNT) {
    int i = b * 256 + tid;
    if (i < NE) atomicAdd(&cnt[dst[i]], 1);
    return;
  }
  b -= PB_COUNT;
  if (b < PB_PADX) {
    int i = b * 256 + tid;
    int r = i / 80, c = i - r * 80;
    x80[i] = (c < 78) ? x[r * 78 + c] : 0.f;
    return;
  }
  b -= PB_PADX;
  if (b < PB_W1) { wdec_elem<78, 78, 96, 80>(W1, wt1H, wt1L, b * 256 + tid); return; }
  b -= PB_W1;
  if (b < PB_W2) { wdec_elem<78, 156, 96, 160>(W2, wt2H, wt2L, b * 256 + tid); return; }
  b -= PB_W2;
  if (b < PB_W3) { wdec_elem<156, 312, 160, 320>(W3, wt3H, wt3L, b * 256 + tid); return; }
  b -= PB_W3;
  if (b < PB_G1) { wdec_elem<312, 1024, 320, 1024>(Wg1, wg1H, wg1L, b * 256 + tid); return; }
  b -= PB_G1;
  if (b < PB_G2) { wdec_elem<1024, 128, 1024, 128>(Wg2, wg2H, wg2L, b * 256 + tid); return; }
  b -= PB_G2;
  if (b < PB_F1) { wdec_elem<130, 1024, 160, 1024>(Wf1, wf1H, wf1L, b * 256 + tid); return; }
  b -= PB_F1;
  wdec_elem<1024, 512, 1024, 512>(Wf2, wf2H, wf2L, b * 256 + tid);
}

// ---------------- CSR scan ----------------
__global__ void k_scan_partial(const int* __restrict__ cnt, int* __restrict__ partial,
                               float* __restrict__ dinv, int n) {
  __shared__ int sdata[1024];
  int tid = threadIdx.x;
  int i = blockIdx.x * 1024 + tid;
  int v = (i < n) ? cnt[i] : 0;
  if (i < n) dinv[i] = rsqrtf((float)(v + 1));  // +1 self loop
  sdata[tid] = v;
  __syncthreads();
  for (int s = 512; s > 0; s >>= 1) {
    if (tid < s) sdata[tid] += sdata[tid + s];
    __syncthreads();
  }
  if (tid == 0) partial[blockIdx.x] = sdata[0];
}

// scan_small folded in: thread 0 serial-sums the (<=49) preceding block partials
__global__ void k_scan_final(const int* __restrict__ cnt, const int* __restrict__ partial,
                             int* __restrict__ rowptr, int n) {
  __shared__ int buf[1024];
  __shared__ int sbase;
  int tid = threadIdx.x;
  int b = blockIdx.x;
  int i = b * 1024 + tid;
  if (tid == 0) {
    int s = 0;
    for (int j = 0; j < b; ++j) s += partial[j];
    sbase = s;
  }
  int v = (i < n) ? cnt[i] : 0;
  buf[tid] = v;
  __syncthreads();
  for (int off = 1; off < 1024; off <<= 1) {
    int t = (tid >= off) ? buf[tid - off] : 0;
    __syncthreads();
    buf[tid] += t;
    __syncthreads();
  }
  int excl = buf[tid] - v + sbase;
  if (i < n) rowptr[i] = excl;
  if (i == n - 1) rowptr[n] = excl + v;  // total
}

// counts DOWN on cnt (consumes it) -> no second memset needed
__global__ void k_fill(const int* __restrict__ src, const int* __restrict__ dst,
                       const int* __restrict__ rowptr, int* __restrict__ cur,
                       const float* __restrict__ dinv,
                       int* __restrict__ csr_src, float* __restrict__ csr_val, int E) {
  int i = blockIdx.x * blockDim.x + threadIdx.x;
  if (i < E) {
    int d = dst[i];
    int old = atomicAdd(&cur[d], -1);
    int pos = rowptr[d] + old - 1;
    int s = src[i];
    csr_src[pos] = s;
    csr_val[pos] = dinv[s];
  }
}

// ---------------- aggregation -> hi/lo bf16, persistent grid-stride waves ----------------
template<int CH, int CHP, int EPW>
__global__ void k_agg_dec8(const float* __restrict__ hin, const int* __restrict__ rowptr,
                           const int* __restrict__ csr_src, const float* __restrict__ csr_val,
                           const float* __restrict__ dinv,
                           unsigned short* __restrict__ Ah, unsigned short* __restrict__ Al, int n) {
  constexpr int Kp = CHP * 8;
  int gw = (blockIdx.x * blockDim.x + threadIdx.x) >> 6;  // global wave id
  int nw = (gridDim.x * blockDim.x) >> 6;                 // total waves
  int lane = threadIdx.x & 63;
  const float4* hin4 = (const float4*)hin;
  int eoff = lane / CH;
  int fl = lane - eoff * CH;
  for (int wid = gw; wid < n; wid += nw) {
    float a[8];
#pragma unroll
    for (int j = 0; j < 8; ++j) a[j] = 0.f;
    int e0 = rowptr[wid], e1 = rowptr[wid + 1];
    if (eoff < EPW) {
      int e = e0 + eoff;
      for (; e + EPW < e1; e += 2 * EPW) {
        int   s0 = csr_src[e];        float w0 = csr_val[e];
        int   s1 = csr_src[e + EPW];  float w1 = csr_val[e + EPW];
        float4 u0 = hin4[(size_t)s0 * (CH * 2) + fl * 2];
        float4 u1 = hin4[(size_t)s0 * (CH * 2) + fl * 2 + 1];
        float4 v0 = hin4[(size_t)s1 * (CH * 2) + fl * 2];
        float4 v1 = hin4[(size_t)s1 * (CH * 2) + fl * 2 + 1];
        a[0] += w0 * u0.x + w1 * v0.x;  a[1] += w0 * u0.y + w1 * v0.y;
        a[2] += w0 * u0.z + w1 * v0.z;  a[3] += w0 * u0.w + w1 * v0.w;
        a[4] += w0 * u1.x + w1 * v1.x;  a[5] += w0 * u1.y + w1 * v1.y;
        a[6] += w0 * u1.z + w1 * v1.z;  a[7] += w0 * u1.w + w1 * v1.w;
      }
      if (e < e1) {
        int s0 = csr_src[e]; float w0 = csr_val[e];
        float4 u0 = hin4[(size_t)s0 * (CH * 2) + fl * 2];
        float4 u1 = hin4[(size_t)s0 * (CH * 2) + fl * 2 + 1];
        a[0] += w0 * u0.x; a[1] += w0 * u0.y; a[2] += w0 * u0.z; a[3] += w0 * u0.w;
        a[4] += w0 * u1.x; a[5] += w0 * u1.y; a[6] += w0 * u1.z; a[7] += w0 * u1.w;
      }
    }
    float r[8];
#pragma unroll
    for (int j = 0; j < 8; ++j) r[j] = a[j];
#pragma unroll
    for (int g = 1; g < EPW; ++g) {
#pragma unroll
      for (int j = 0; j < 8; ++j) r[j] += __shfl(a[j], lane + g * CH);
    }
    if (lane < CH) {
      float dv = dinv[wid];
      float4 s0 = hin4[(size_t)wid * (CH * 2) + lane * 2];
      float4 s1 = hin4[(size_t)wid * (CH * 2) + lane * 2 + 1];
      float v[8] = { dv * (r[0] + dv * s0.x), dv * (r[1] + dv * s0.y),
                     dv * (r[2] + dv * s0.z), dv * (r[3] + dv * s0.w),
                     dv * (r[4] + dv * s1.x), dv * (r[5] + dv * s1.y),
                     dv * (r[6] + dv * s1.z), dv * (r[7] + dv * s1.w) };
      us8 hi, lo;
#pragma unroll
      for (int j = 0; j < 8; ++j) {
        unsigned short h = bf16_rne(v[j]);
        hi[j] = h;
        lo[j] = bf16_rne(v[j] - bf16_to_f(h));
      }
      size_t base = (size_t)wid * Kp + lane * 8;
      *(us8*)(Ah + base) = hi;
      *(us8*)(Al + base) = lo;
    } else if (lane >= 60) {
      int c = CH + (lane - 60);   // zero-fill K-pad chunks
      if (c < CHP) {
        us8 z;
#pragma unroll
        for (int j = 0; j < 8; ++j) z[j] = 0;
        size_t base = (size_t)wid * Kp + (size_t)c * 8;
        *(us8*)(Ah + base) = z;
        *(us8*)(Al + base) = z;
      }
    }
  }
}

// ---------------- conv MFMA matmul: 128 rows x NB cols per block, 32 rows/wave ----------------
// Full W-panel in LDS once; ALL A-fragments prefetched to registers; single barrier.
// Bijective XCD-chunked blockIdx swizzle keeps NCB blocks sharing an A row-panel on one XCD.
// POOL: per-graph segmented max -> global atomicMax (u32, values >= 0).
template<int Kp, int Np, int NB, bool POOL>
__global__ __launch_bounds__(256) void k_mm_mfma(const unsigned short* __restrict__ Ahp,
                                                 const unsigned short* __restrict__ Alp,
                                                 const unsigned short* __restrict__ Wh,
                                                 const unsigned short* __restrict__ Wl,
                                                 const float* __restrict__ bias,
                                                 float* __restrict__ C,
                                                 const int* __restrict__ batch,
                                                 unsigned int* __restrict__ poolU,
                                                 int N, int M) {
  constexpr int NCB = Np / NB;
  constexpr int NT = NB / 16;
  constexpr int KS = Kp / 32;
  constexpr int KC = Kp / 8;       // 16B chunks per row
  constexpr int PITCH = Kp + 8;    // ushorts
  __shared__ unsigned short wlds[2 * NB * PITCH];
  unsigned short* whi = wlds;
  unsigned short* wlo = wlds + NB * PITCH;
  int tid = threadIdx.x;
  int w = tid >> 6, l = tid & 63;
  int m = l & 15, kg = l >> 4;
  // bijective XCD-chunked swizzle (m204)
  int nwg = gridDim.x;
  int orig = blockIdx.x;
  int qd = nwg >> 3, rm = nwg & 7;
  int xcd = orig & 7, seq = orig >> 3;
  int wgid = (xcd < rm ? xcd * (qd + 1) : rm * (qd + 1) + (xcd - rm) * qd) + seq;
  int bc = wgid % NCB;
  int br = wgid / NCB;
  int row0 = br * 128;
  // stage FULL W-panel hi+lo once
  for (int i = tid; i < 2 * NB * KC; i += 256) {
    int mtx = i / (NB * KC);
    int j = i - mtx * (NB * KC);
    int n = j / KC, qq = j - n * KC;
    const unsigned short* src = mtx ? Wl : Wh;
    unsigned short* dst = mtx ? wlo : whi;
    *(us8*)&dst[n * PITCH + qq * 8] = *(const us8*)&src[(size_t)(bc * NB + n) * Kp + qq * 8];
  }
  // prefetch ALL A fragments into registers
  frag8 ah0[KS], al0[KS], ah1[KS], al1[KS];
  size_t arow0 = (size_t)(row0 + 32 * w + m) * Kp + kg * 8;
  size_t arow1 = arow0 + (size_t)16 * Kp;
#pragma unroll
  for (int kk = 0; kk < KS; ++kk) {
    ah0[kk] = *(const frag8*)(Ahp + arow0 + kk * 32);
    al0[kk] = *(const frag8*)(Alp + arow0 + kk * 32);
    ah1[kk] = *(const frag8*)(Ahp + arow1 + kk * 32);
    al1[kk] = *(const frag8*)(Alp + arow1 + kk * 32);
  }
  __syncthreads();

  f32x4 zero4 = {0.f, 0.f, 0.f, 0.f};
  f32x4 acc0[NT], acc1[NT];
#pragma unroll
  for (int t = 0; t < NT; ++t) { acc0[t] = zero4; acc1[t] = zero4; }

#pragma unroll
  for (int kk = 0; kk < KS; ++kk) {   // pure LDS+MFMA
#pragma unroll
    for (int t = 0; t < NT; ++t) {
      int n = t * 16 + m;
      int co = kk * 32 + kg * 8;
      frag8 bh = *(const frag8*)&whi[n * PITCH + co];
      frag8 bl = *(const frag8*)&wlo[n * PITCH + co];
      acc0[t] = __builtin_amdgcn_mfma_f32_16x16x32_bf16(ah0[kk], bh, acc0[t], 0, 0, 0);
      acc0[t] = __builtin_amdgcn_mfma_f32_16x16x32_bf16(ah0[kk], bl, acc0[t], 0, 0, 0);
      acc0[t] = __builtin_amdgcn_mfma_f32_16x16x32_bf16(al0[kk], bh, acc0[t], 0, 0, 0);
      acc1[t] = __builtin_amdgcn_mfma_f32_16x16x32_bf16(ah1[kk], bh, acc1[t], 0, 0, 0);
      acc1[t] = __builtin_amdgcn_mfma_f32_16x16x32_bf16(ah1[kk], bl, acc1[t], 0, 0, 0);
      acc1[t] = __builtin_amdgcn_mfma_f32_16x16x32_bf16(al1[kk], bh, acc1[t], 0, 0, 0);
    }
  }
  // epilogue: C/D layout (m89-verified): col = lane&15, row-in-frag = (lane>>4)*4 + reg
  if (!POOL) {
#pragma unroll
    for (int t = 0; t < NT; ++t) {
      int col = bc * NB + t * 16 + m;
      float b = (col < N) ? bias[col] : 0.f;
#pragma unroll
      for (int r = 0; r < 4; ++r) {
        int row = row0 + 32 * w + kg * 4 + r;
        float v0 = fmaxf(acc0[t][r] + b, 0.f);
        float v1 = fmaxf(acc1[t][r] + b, 0.f);
        C[(size_t)row * Np + col] = (col < N) ? v0 : 0.f;
        C[(size_t)(row + 16) * Np + col] = (col < N) ? v1 : 0.f;
      }
    }
  } else {
    int gA = batch[row0];  // block spans <=2 graphs (min graph size ~195 > 128)
    int rbase = row0 + 32 * w + kg * 4;
    int cls[8];  // 0 invalid, 1 graph A, 2 graph A+1
#pragma unroll
    for (int r = 0; r < 4; ++r) {
      int ra = rbase + r, rb = rbase + 16 + r;
      cls[r]     = (ra < M) ? ((batch[ra] == gA) ? 1 : 2) : 0;
      cls[4 + r] = (rb < M) ? ((batch[rb] == gA) ? 1 : 2) : 0;
    }
#pragma unroll
    for (int t = 0; t < NT; ++t) {
      int col = bc * NB + t * 16 + m;
      float b = (col < N) ? bias[col] : 0.f;
      float m0 = 0.f, m1 = 0.f;
#pragma unroll
      for (int r = 0; r < 4; ++r) {
        float v0 = fmaxf(acc0[t][r] + b, 0.f);
        float v1 = fmaxf(acc1[t][r] + b, 0.f);
        if (cls[r] == 1)     m0 = fmaxf(m0, v0); else if (cls[r] == 2)     m1 = fmaxf(m1, v0);
        if (cls[4 + r] == 1) m0 = fmaxf(m0, v1); else if (cls[4 + r] == 2) m1 = fmaxf(m1, v1);
      }
      m0 = fmaxf(m0, __shfl_xor(m0, 16)); m0 = fmaxf(m0, __shfl_xor(m0, 32));
      m1 = fmaxf(m1, __shfl_xor(m1, 16)); m1 = fmaxf(m1, __shfl_xor(m1, 32));
      if (l < 16 && col < N) {
        if (m0 > 0.f) atomicMax(&poolU[(size_t)gA * 320 + col], __float_as_uint(m0));
        if (m1 > 0.f) atomicMax(&poolU[(size_t)(gA + 1) * 320 + col], __float_as_uint(m1));
      }
    }
  }
}

// ---------------- head MFMA v2: conv-style. BM=64 (16 rows/wave), NB cols, optional K-split ----------------
template<int Kp, int Np, int NB, int KSPLIT, bool RELU, int OUTMODE, int SOUT, bool AU32>
__global__ __launch_bounds__(256) void k_hmm2(const unsigned short* __restrict__ Ahp,
                                              const unsigned short* __restrict__ Alp,
                                              const unsigned int* __restrict__ Au,
                                              const unsigned short* __restrict__ Wh,
                                              const unsigned short* __restrict__ Wl,
                                              const float* __restrict__ bias,
                                              float* __restrict__ partOrC,
                                              unsigned short* __restrict__ OutH,
                                              unsigned short* __restrict__ OutL) {
  constexpr int NCB = Np / NB;
  constexpr int NT = NB / 16;
  constexpr int KS = Kp / 32 / KSPLIT;
  constexpr int KSL = KS * 32;        // K-slice ushorts
  constexpr int CH8 = KSL / 8;
  constexpr int PITCH = KSL + 8;
  __shared__ unsigned short wlds[2 * NB * PITCH];
  unsigned short* whi = wlds;
  unsigned short* wlo = wlds + NB * PITCH;
  int tid = threadIdx.x;
  int w = tid >> 6, l = tid & 63;
  int m = l & 15, kg = l >> 4;
  int bc = blockIdx.x % NCB;
  int kc = (blockIdx.x / NCB) % KSPLIT;
  int br = blockIdx.x / (NCB * KSPLIT);
  int row0 = br * 64;
  int k0 = kc * KSL;
  // stage W K-slice hi+lo once
  for (int i = tid; i < 2 * NB * CH8; i += 256) {
    int mtx = i / (NB * CH8);
    int j = i - mtx * (NB * CH8);
    int n = j / CH8, q = j - n * CH8;
    const unsigned short* src = mtx ? Wl : Wh;
    unsigned short* dst = mtx ? wlo : whi;
    *(us8*)&dst[n * PITCH + q * 8] = *(const us8*)&src[(size_t)(bc * NB + n) * Kp + k0 + q * 8];
  }
  // prefetch A fragments
  frag8 ah[KS], al[KS];
  int arow = row0 + 16 * w + m;
  if (AU32) {
#pragma unroll
    for (int kk = 0; kk < KS; ++kk) {
      u32x8 uv = *(const u32x8*)(Au + (size_t)arow * Kp + k0 + kk * 32 + kg * 8);
      frag8 h8, l8;
#pragma unroll
      for (int j = 0; j < 8; ++j) {
        float v = __uint_as_float(uv[j]);
        unsigned short hh = bf16_rne(v);
        h8[j] = (short)hh;
        l8[j] = (short)bf16_rne(v - bf16_to_f(hh));
      }
      ah[kk] = h8; al[kk] = l8;
    }
  } else {
    size_t abase = (size_t)arow * Kp + k0 + kg * 8;
#pragma unroll
    for (int kk = 0; kk < KS; ++kk) {
      ah[kk] = *(const frag8*)(Ahp + abase + kk * 32);
      al[kk] = *(const frag8*)(Alp + abase + kk * 32);
    }
  }
  __syncthreads();

  f32x4 acc[NT];
#pragma unroll
  for (int t = 0; t < NT; ++t) acc[t] = (f32x4){0.f, 0.f, 0.f, 0.f};
#pragma unroll
  for (int kk = 0; kk < KS; ++kk) {
#pragma unroll
    for (int t = 0; t < NT; ++t) {
      int n = t * 16 + m;
      int co = kk * 32 + kg * 8;
      frag8 bh = *(const frag8*)&whi[n * PITCH + co];
      frag8 bl = *(const frag8*)&wlo[n * PITCH + co];
      acc[t] = __builtin_amdgcn_mfma_f32_16x16x32_bf16(ah[kk], bh, acc[t], 0, 0, 0);
      acc[t] = __builtin_amdgcn_mfma_f32_16x16x32_bf16(ah[kk], bl, acc[t], 0, 0, 0);
      acc[t] = __builtin_amdgcn_mfma_f32_16x16x32_bf16(al[kk], bh, acc[t], 0, 0, 0);
    }
  }
#pragma unroll
  for (int t = 0; t < NT; ++t) {
    int col = bc * NB + t * 16 + m;
#pragma unroll
    for (int r = 0; r < 4; ++r) {
      int row = row0 + 16 * w + kg * 4 + r;
      float v = acc[t][r];
      if (KSPLIT > 1) {
        partOrC[((size_t)(kc * 256) + row) * Np + col] = v;
      } else {
        v += bias[col];
        if (RELU) v = fmaxf(v, 0.f);
        if (OUTMODE == 0) {
          partOrC[(size_t)row * SOUT + col] = v;
        } else {
          unsigned short h = bf16_rne(v);
          OutH[(size_t)row * SOUT + col] = h;
          OutL[(size_t)row * SOUT + col] = bf16_rne(v - bf16_to_f(h));
        }
      }
    }
  }
}

// combine K-split partials: C = act(sum_kc part + bias); optional T/P insert (cols 128/129)
template<int Np, int KSPLIT, bool RELU, int OUTMODE, int SOUT, bool TP>
__global__ void k_comb(const float* __restrict__ part, const float* __restrict__ bias,
                       float* __restrict__ Cf, unsigned short* __restrict__ OutH,
                       unsigned short* __restrict__ OutL,
                       const float* __restrict__ T, const float* __restrict__ P) {
  int idx = blockIdx.x * 256 + threadIdx.x;   // over 256*Np
  int row = idx / Np, col = idx - row * Np;
  float s = bias[col];
#pragma unroll
  for (int kc = 0; kc < KSPLIT; ++kc) s += part[((size_t)(kc * 256) + row) * Np + col];
  if (RELU) s = fmaxf(s, 0.f);
  if (OUTMODE == 0) {
    Cf[(size_t)row * SOUT + col] = s;
  } else {
    unsigned short h = bf16_rne(s);
    OutH[(size_t)row * SOUT + col] = h;
    OutL[(size_t)row * SOUT + col] = bf16_rne(s - bf16_to_f(h));
  }
  if (TP && idx < 256) {
    int g = idx;
    float tv = T[g], pv = P[g];
    unsigned short th = bf16_rne(tv), ph = bf16_rne(pv);
    OutH[(size_t)g * SOUT + 128] = th;
    OutL[(size_t)g * SOUT + 128] = bf16_rne(tv - bf16_to_f(th));
    OutH[(size_t)g * SOUT + 129] = ph;
    OutL[(size_t)g * SOUT + 129] = bf16_rne(pv - bf16_to_f(ph));
  }
}

__global__ void k_final(const float* __restrict__ g4, const float* __restrict__ Wo,
                        const float* __restrict__ bo, float* __restrict__ out) {
  int g = blockIdx.x;
  int lane = threadIdx.x;  // 64
  float acc = 0.f;
#pragma unroll
  for (int u = 0; u < 8; ++u) {
    int k = lane + u * 64;
    acc += g4[(size_t)g * 512 + k] * Wo[k];
  }
  for (int s = 32; s > 0; s >>= 1) acc += __shfl_down(acc, s);
  if (lane == 0) out[g] = acc + bo[0];
}

// ---------------- launch ----------------
extern "C" void kernel_launch(void* const* d_in, const int* in_sizes, int n_in,
                              void* d_out, int out_size, void* d_ws, size_t ws_size,
                              hipStream_t stream) {
  const float* x   = (const float*)d_in[0];
  const int*   ei  = (const int*)d_in[1];
  const int*   bat = (const int*)d_in[2];
  const float* T   = (const float*)d_in[3];
  const float* P   = (const float*)d_in[4];
  const float* W1  = (const float*)d_in[5];
  const float* b1  = (const float*)d_in[6];
  const float* W2  = (const float*)d_in[7];
  const float* b2  = (const float*)d_in[8];
  const float* W3  = (const float*)d_in[9];
  const float* b3  = (const float*)d_in[10];
  const float* Wg1 = (const float*)d_in[11];
  const float* bg1 = (const float*)d_in[12];
  const float* Wg2 = (const float*)d_in[13];
  const float* bg2 = (const float*)d_in[14];
  const float* Wf1 = (const float*)d_in[15];
  const float* bf1 = (const float*)d_in[16];
  const float* Wf2 = (const float*)d_in[17];
  const float* bf2 = (const float*)d_in[18];
  const float* Wo  = (const float*)d_in[19];
  const float* bo  = (const float*)d_in[20];
  float* out = (float*)d_out;

  char* ws = (char*)d_ws;
  size_t off = 0;
  auto alloc = [&](size_t bytes) -> void* {
    void* p = ws + off;
    off = (off + bytes + 255) & ~(size_t)255;
    return p;
  };
  // ---- zero region (one memset): cnt + poolU + xcH + xcL ----
  char* zero_base = ws + off;
  int*           cnt   = (int*)alloc((size_t)NN * 4);
  unsigned int*  poolU = (unsigned int*)alloc((size_t)256 * 320 * 4);
  unsigned short* xcH  = (unsigned short*)alloc((size_t)256 * 160 * 2);
  unsigned short* xcL  = (unsigned short*)alloc((size_t)256 * 160 * 2);
  size_t zero_bytes = (size_t)((ws + off) - zero_base);
  // ---- conv buffers (overlays: x80/h1 at +0, h2 at +(NN+64)*80; h3 never materialized) ----
  float* Rbig    = (float*)alloc((size_t)(NN + 64) * 320 * 4);
  float* x80     = Rbig;
  float* h1      = Rbig;
  float* h2      = Rbig + (size_t)(NN + 64) * 80;
  unsigned short* aggH = (unsigned short*)alloc((size_t)(NN + 64) * 160 * 2);
  unsigned short* aggL = (unsigned short*)alloc((size_t)(NN + 64) * 160 * 2);
  unsigned short* wt1H = (unsigned short*)alloc((size_t)96 * 80 * 2);
  unsigned short* wt1L = (unsigned short*)alloc((size_t)96 * 80 * 2);
  unsigned short* wt2H = (unsigned short*)alloc((size_t)96 * 160 * 2);
  unsigned short* wt2L = (unsigned short*)alloc((size_t)96 * 160 * 2);
  unsigned short* wt3H = (unsigned short*)alloc((size_t)160 * 320 * 2);
  unsigned short* wt3L = (unsigned short*)alloc((size_t)160 * 320 * 2);
  int*   rowptr  = (int*)alloc((size_t)(NN + 1) * 4);
  int*   partial = (int*)alloc(64 * 4);
  int*   csr_src = (int*)alloc((size_t)NE * 4);
  float* csr_val = (float*)alloc((size_t)NE * 4);
  float* dinv    = (float*)alloc((size_t)NN * 4);
  // head weights hi/lo
  unsigned short* wg1H = (unsigned short*)alloc((size_t)1024 * 320 * 2);
  unsigned short* wg1L = (unsigned short*)alloc((size_t)1024 * 320 * 2);
  unsigned short* wg2H = (unsigned short*)alloc((size_t)128 * 1024 * 2);
  unsigned short* wg2L = (unsigned short*)alloc((size_t)128 * 1024 * 2);
  unsigned short* wf1H = (unsigned short*)alloc((size_t)1024 * 160 * 2);
  unsigned short* wf1L = (unsigned short*)alloc((size_t)1024 * 160 * 2);
  unsigned short* wf2H = (unsigned short*)alloc((size_t)512 * 1024 * 2);
  unsigned short* wf2L = (unsigned short*)alloc((size_t)512 * 1024 * 2);
  // head activations hi/lo
  unsigned short* g1H = (unsigned short*)alloc((size_t)256 * 1024 * 2);
  unsigned short* g1L = (unsigned short*)alloc((size_t)256 * 1024 * 2);
  unsigned short* g3H = (unsigned short*)alloc((size_t)256 * 1024 * 2);
  unsigned short* g3L = (unsigned short*)alloc((size_t)256 * 1024 * 2);
  float* g4      = (float*)alloc((size_t)256 * 512 * 4);
  float* hpart   = (float*)alloc((size_t)8 * 256 * 512 * 4);  // K-split partials
  (void)ws_size; (void)in_sizes; (void)n_in; (void)out_size;

  const int* srcp = ei;        // edge_index[0]
  const int* dstp = ei + NE;   // edge_index[1]

  // single zero-init (cnt histogram; poolU >=0 maxes; xc pad cols)
  hipMemsetAsync(zero_base, 0, zero_bytes, stream);

  // prep: edge count + x-pad + all weight decompositions (concurrent)
  k_prep<<<PREP_BLOCKS, 256, 0, stream>>>(dstp, cnt, x, x80,
                                          W1, wt1H, wt1L, W2, wt2H, wt2L, W3, wt3H, wt3L,
                                          Wg1, wg1H, wg1L, Wg2, wg2H, wg2L,
                                          Wf1, wf1H, wf1L, Wf2, wf2H, wf2L);
  // CSR build
  int nb = (NN + 1023) / 1024;
  k_scan_partial<<<nb, 1024, 0, stream>>>(cnt, partial, dinv, NN);
  k_scan_final<<<nb, 1024, 0, stream>>>(cnt, partial, rowptr, NN);
  k_fill<<<(NE + 255) / 256, 256, 0, stream>>>(srcp, dstp, rowptr, cnt, dinv, csr_src, csr_val, NE);

  const int aggBlocks = 2048;                 // persistent: 8192 waves grid-stride over nodes
  const int mmRows128 = (NN + 127) / 128;     // 391 (BM=128)

  // conv1: agg(x80) -> Kp=96; h1 = relu(agg@W1 + b1), Np=80, NB=80
  k_agg_dec8<10, 12, 6><<<aggBlocks, 256, 0, stream>>>(x80, rowptr, csr_src, csr_val, dinv, aggH, aggL, NN);
  k_mm_mfma<96, 80, 80, false><<<mmRows128, 256, 0, stream>>>(
      aggH, aggL, wt1H, wt1L, b1, h1, nullptr, nullptr, 78, NN);
  // conv2: NB=80, NCB=2
  k_agg_dec8<10, 12, 6><<<aggBlocks, 256, 0, stream>>>(h1, rowptr, csr_src, csr_val, dinv, aggH, aggL, NN);
  k_mm_mfma<96, 160, 80, false><<<mmRows128 * 2, 256, 0, stream>>>(
      aggH, aggL, wt2H, wt2L, b2, h2, nullptr, nullptr, 156, NN);
  // conv3: fused pool epilogue, NB=64 (NCB=5, LDS 43KB -> 3 blocks/CU)
  k_agg_dec8<20, 20, 3><<<aggBlocks, 256, 0, stream>>>(h2, rowptr, csr_src, csr_val, dinv, aggH, aggL, NN);
  k_mm_mfma<160, 320, 64, true><<<mmRows128 * 5, 256, 0, stream>>>(
      aggH, aggL, wt3H, wt3L, b3, nullptr, bat, poolU, 312, NN);

  // head L1: g1 = relu(pool @ Wg1 + bg1)  [256,320]x[320,1024]; A from poolU (u32 decompose)
  k_hmm2<320, 1024, 32, 1, true, 1, 1024, true><<<4 * 32, 256, 0, stream>>>(
      nullptr, nullptr, poolU, wg1H, wg1L, bg1, nullptr, g1H, g1L);
  // head L2: g2 = g1 @ Wg2 + bg2   [256,1024]x[1024,128], 8-way K-split
  k_hmm2<1024, 128, 32, 8, false, 0, 0, false><<<4 * 4 * 8, 256, 0, stream>>>(
      g1H, g1L, nullptr, wg2H, wg2L, nullptr, hpart, nullptr, nullptr);
  k_comb<128, 8, false, 1, 160, true><<<128, 256, 0, stream>>>(hpart, bg2, nullptr, xcH, xcL, T, P);
  // head L3: g3 = relu(xc @ Wf1 + bf1)   [256,160]x[160,1024]
  k_hmm2<160, 1024, 32, 1, true, 1, 1024, false><<<4 * 32, 256, 0, stream>>>(
      xcH, xcL, nullptr, wf1H, wf1L, bf1, nullptr, g3H, g3L);
  // head L4: g4 = relu(g3 @ Wf2 + bf2)   [256,1024]x[1024,512], 8-way K-split
  k_hmm2<1024, 512, 32, 8, false, 0, 0, false><<<4 * 16 * 8, 256, 0, stream>>>(
      g3H, g3L, nullptr, wf2H, wf2L, nullptr, hpart, nullptr, nullptr);
  k_comb<512, 8, true, 0, 512, false><<<512, 256, 0, stream>>>(hpart, bf2, g4, nullptr, nullptr, nullptr, nullptr);
  // final: out = g4 @ Wo + bo
  k_final<<<NG, 64, 0, stream>>>(g4, Wo, bo, out);
}

// Round 14
// 282.217 us; speedup vs baseline: 1.0592x; 1.0592x over previous
//
#include <hip/hip_runtime.h>
#include <cstdint>
#include <cstddef>

static constexpr int NN = 50000;   // nodes
static constexpr int NE = 500000;  // edges
static constexpr int NG = 256;     // graphs

typedef short  frag8  __attribute__((ext_vector_type(8)));   // 8 bf16 (4 VGPRs) MFMA operand
typedef float  f32x4  __attribute__((ext_vector_type(4)));
typedef unsigned short us8 __attribute__((ext_vector_type(8)));
typedef unsigned int   u32x8 __attribute__((ext_vector_type(8)));

__device__ __forceinline__ unsigned short bf16_rne(float f) {
  unsigned u = __builtin_bit_cast(unsigned, f);
  u += 0x7fffu + ((u >> 16) & 1u);
  return (unsigned short)(u >> 16);
}
__device__ __forceinline__ float bf16_to_f(unsigned short h) {
  unsigned u = ((unsigned)h) << 16;
  return __builtin_bit_cast(float, u);
}

// ---------------- W decompose helper: W[K][N] f32 -> WT_hi/lo[Np][Kp] bf16 ----------------
template<int K, int N, int Kp, int Np>
__device__ __forceinline__ void wdec_elem(const float* __restrict__ W,
                                          unsigned short* __restrict__ Wh,
                                          unsigned short* __restrict__ Wl, int idx) {
  if (idx >= Np * Kp) return;
  int n = idx / Kp, k = idx - n * Kp;
  float v = (n < N && k < K) ? W[k * N + n] : 0.f;
  unsigned short h = bf16_rne(v);
  Wh[idx] = h;
  Wl[idx] = bf16_rne(v - bf16_to_f(h));
}

// ---------------- prep mega-kernel: edge count + x-pad + all 7 weight decomps ----------------
static constexpr int PB_COUNT = (NE + 255) / 256;        // 1954
static constexpr int PB_PADX  = (NN * 80) / 256;         // 15625
static constexpr int PB_W1 = (96 * 80) / 256;            // 30
static constexpr int PB_W2 = (96 * 160) / 256;           // 60
static constexpr int PB_W3 = (160 * 320) / 256;          // 200
static constexpr int PB_G1 = (320 * 1024) / 256;         // 1280
static constexpr int PB_G2 = (1024 * 128) / 256;         // 512
static constexpr int PB_F1 = (160 * 1024) / 256;         // 640
static constexpr int PB_F2 = (1024 * 512) / 256;         // 2048
static constexpr int PREP_BLOCKS = PB_COUNT + PB_PADX + PB_W1 + PB_W2 + PB_W3 + PB_G1 + PB_G2 + PB_F1 + PB_F2;

__global__ void k_prep(const int* __restrict__ dst, int* __restrict__ cnt,
                       const float* __restrict__ x, float* __restrict__ x80,
                       const float* __restrict__ W1, unsigned short* wt1H, unsigned short* wt1L,
                       const float* __restrict__ W2, unsigned short* wt2H, unsigned short* wt2L,
                       const float* __restrict__ W3, unsigned short* wt3H, unsigned short* wt3L,
                       const float* __restrict__ Wg1, unsigned short* wg1H, unsigned short* wg1L,
                       const float* __restrict__ Wg2, unsigned short* wg2H, unsigned short* wg2L,
                       const float* __restrict__ Wf1, unsigned short* wf1H, unsigned short* wf1L,
                       const float* __restrict__ Wf2, unsigned short* wf2H, unsigned short* wf2L) {
  int b = blockIdx.x, tid = threadIdx.x;
  if (b < PB_COUNT) {
    int i = b * 256 + tid;
    if (i < NE) atomicAdd(&cnt[dst[i]], 1);
    return;
  }
  b -= PB_COUNT;
  if (b < PB_PADX) {
    int i = b * 256 + tid;
    int r = i / 80, c = i - r * 80;
    x80[i] = (c < 78) ? x[r * 78 + c] : 0.f;
    return;
  }
  b -= PB_PADX;
  if (b < PB_W1) { wdec_elem<78, 78, 96, 80>(W1, wt1H, wt1L, b * 256 + tid); return; }
  b -= PB_W1;
  if (b < PB_W2) { wdec_elem<78, 156, 96, 160>(W2, wt2H, wt2L, b * 256 + tid); return; }
  b -= PB_W2;
  if (b < PB_W3) { wdec_elem<156, 312, 160, 320>(W3, wt3H, wt3L, b * 256 + tid); return; }
  b -= PB_W3;
  if (b < PB_G1) { wdec_elem<312, 1024, 320, 1024>(Wg1, wg1H, wg1L, b * 256 + tid); return; }
  b -= PB_G1;
  if (b < PB_G2) { wdec_elem<1024, 128, 1024, 128>(Wg2, wg2H, wg2L, b * 256 + tid); return; }
  b -= PB_G2;
  if (b < PB_F1) { wdec_elem<130, 1024, 160, 1024>(Wf1, wf1H, wf1L, b * 256 + tid); return; }
  b -= PB_F1;
  wdec_elem<1024, 512, 1024, 512>(Wf2, wf2H, wf2L, b * 256 + tid);
}

// ---------------- CSR scan ----------------
__global__ void k_scan_partial(const int* __restrict__ cnt, int* __restrict__ partial,
                               float* __restrict__ dinv, int n) {
  __shared__ int sdata[1024];
  int tid = threadIdx.x;
  int i = blockIdx.x * 1024 + tid;
  int v = (i < n) ? cnt[i] : 0;
  if (i < n) dinv[i] = rsqrtf((float)(v + 1));  // +1 self loop
  sdata[tid] = v;
  __syncthreads();
  for (int s = 512; s > 0; s >>= 1) {
    if (tid < s) sdata[tid] += sdata[tid + s];
    __syncthreads();
  }
  if (tid == 0) partial[blockIdx.x] = sdata[0];
}

// scan_small folded in: thread 0 serial-sums the (<=49) preceding block partials
__global__ void k_scan_final(const int* __restrict__ cnt, const int* __restrict__ partial,
                             int* __restrict__ rowptr, int n) {
  __shared__ int buf[1024];
  __shared__ int sbase;
  int tid = threadIdx.x;
  int b = blockIdx.x;
  int i = b * 1024 + tid;
  if (tid == 0) {
    int s = 0;
    for (int j = 0; j < b; ++j) s += partial[j];
    sbase = s;
  }
  int v = (i < n) ? cnt[i] : 0;
  buf[tid] = v;
  __syncthreads();
  for (int off = 1; off < 1024; off <<= 1) {
    int t = (tid >= off) ? buf[tid - off] : 0;
    __syncthreads();
    buf[tid] += t;
    __syncthreads();
  }
  int excl = buf[tid] - v + sbase;
  if (i < n) rowptr[i] = excl;
  if (i == n - 1) rowptr[n] = excl + v;  // total
}

// counts DOWN on cnt (consumes it) -> no second memset needed
__global__ void k_fill(const int* __restrict__ src, const int* __restrict__ dst,
                       const int* __restrict__ rowptr, int* __restrict__ cur,
                       const float* __restrict__ dinv,
                       int* __restrict__ csr_src, float* __restrict__ csr_val, int E) {
  int i = blockIdx.x * blockDim.x + threadIdx.x;
  if (i < E) {
    int d = dst[i];
    int old = atomicAdd(&cur[d], -1);
    int pos = rowptr[d] + old - 1;
    int s = src[i];
    csr_src[pos] = s;
    csr_val[pos] = dinv[s];
  }
}

// ---------------- aggregation -> hi/lo bf16, 8-float chunks, one wave per node (one-shot) ----------------
template<int CH, int CHP, int EPW>
__global__ void k_agg_dec8(const float* __restrict__ hin, const int* __restrict__ rowptr,
                           const int* __restrict__ csr_src, const float* __restrict__ csr_val,
                           const float* __restrict__ dinv,
                           unsigned short* __restrict__ Ah, unsigned short* __restrict__ Al, int n) {
  constexpr int Kp = CHP * 8;
  int wid = (blockIdx.x * blockDim.x + threadIdx.x) >> 6;  // one wave per node
  int lane = threadIdx.x & 63;
  if (wid >= n) return;
  const float4* hin4 = (const float4*)hin;
  int eoff = lane / CH;
  int fl = lane - eoff * CH;
  float a[8];
#pragma unroll
  for (int j = 0; j < 8; ++j) a[j] = 0.f;
  int e0 = rowptr[wid], e1 = rowptr[wid + 1];
  if (eoff < EPW) {
    int e = e0 + eoff;
    for (; e + EPW < e1; e += 2 * EPW) {
      int   s0 = csr_src[e];        float w0 = csr_val[e];
      int   s1 = csr_src[e + EPW];  float w1 = csr_val[e + EPW];
      float4 u0 = hin4[(size_t)s0 * (CH * 2) + fl * 2];
      float4 u1 = hin4[(size_t)s0 * (CH * 2) + fl * 2 + 1];
      float4 v0 = hin4[(size_t)s1 * (CH * 2) + fl * 2];
      float4 v1 = hin4[(size_t)s1 * (CH * 2) + fl * 2 + 1];
      a[0] += w0 * u0.x + w1 * v0.x;  a[1] += w0 * u0.y + w1 * v0.y;
      a[2] += w0 * u0.z + w1 * v0.z;  a[3] += w0 * u0.w + w1 * v0.w;
      a[4] += w0 * u1.x + w1 * v1.x;  a[5] += w0 * u1.y + w1 * v1.y;
      a[6] += w0 * u1.z + w1 * v1.z;  a[7] += w0 * u1.w + w1 * v1.w;
    }
    if (e < e1) {
      int s0 = csr_src[e]; float w0 = csr_val[e];
      float4 u0 = hin4[(size_t)s0 * (CH * 2) + fl * 2];
      float4 u1 = hin4[(size_t)s0 * (CH * 2) + fl * 2 + 1];
      a[0] += w0 * u0.x; a[1] += w0 * u0.y; a[2] += w0 * u0.z; a[3] += w0 * u0.w;
      a[4] += w0 * u1.x; a[5] += w0 * u1.y; a[6] += w0 * u1.z; a[7] += w0 * u1.w;
    }
  }
  float r[8];
#pragma unroll
  for (int j = 0; j < 8; ++j) r[j] = a[j];
#pragma unroll
  for (int g = 1; g < EPW; ++g) {
#pragma unroll
    for (int j = 0; j < 8; ++j) r[j] += __shfl(a[j], lane + g * CH);
  }
  if (lane < CH) {
    float dv = dinv[wid];
    float4 s0 = hin4[(size_t)wid * (CH * 2) + lane * 2];
    float4 s1 = hin4[(size_t)wid * (CH * 2) + lane * 2 + 1];
    float v[8] = { dv * (r[0] + dv * s0.x), dv * (r[1] + dv * s0.y),
                   dv * (r[2] + dv * s0.z), dv * (r[3] + dv * s0.w),
                   dv * (r[4] + dv * s1.x), dv * (r[5] + dv * s1.y),
                   dv * (r[6] + dv * s1.z), dv * (r[7] + dv * s1.w) };
    us8 hi, lo;
#pragma unroll
    for (int j = 0; j < 8; ++j) {
      unsigned short h = bf16_rne(v[j]);
      hi[j] = h;
      lo[j] = bf16_rne(v[j] - bf16_to_f(h));
    }
    size_t base = (size_t)wid * Kp + lane * 8;
    *(us8*)(Ah + base) = hi;
    *(us8*)(Al + base) = lo;
  } else if (lane >= 60) {
    int c = CH + (lane - 60);   // zero-fill K-pad chunks
    if (c < CHP) {
      us8 z;
#pragma unroll
      for (int j = 0; j < 8; ++j) z[j] = 0;
      size_t base = (size_t)wid * Kp + (size_t)c * 8;
      *(us8*)(Ah + base) = z;
      *(us8*)(Al + base) = z;
    }
  }
}

// ---------------- conv MFMA matmul: 128 rows x NB cols per block, 32 rows/wave ----------------
// Full W-panel in LDS once; ALL A-fragments prefetched to registers; single barrier.
// Bijective XCD-chunked blockIdx swizzle keeps NCB blocks sharing an A row-panel on one XCD.
// POOL: per-graph segmented max -> global atomicMax (u32, values >= 0).
template<int Kp, int Np, int NB, bool POOL>
__global__ __launch_bounds__(256) void k_mm_mfma(const unsigned short* __restrict__ Ahp,
                                                 const unsigned short* __restrict__ Alp,
                                                 const unsigned short* __restrict__ Wh,
                                                 const unsigned short* __restrict__ Wl,
                                                 const float* __restrict__ bias,
                                                 float* __restrict__ C,
                                                 const int* __restrict__ batch,
                                                 unsigned int* __restrict__ poolU,
                                                 int N, int M) {
  constexpr int NCB = Np / NB;
  constexpr int NT = NB / 16;
  constexpr int KS = Kp / 32;
  constexpr int KC = Kp / 8;       // 16B chunks per row
  constexpr int PITCH = Kp + 8;    // ushorts
  __shared__ unsigned short wlds[2 * NB * PITCH];
  unsigned short* whi = wlds;
  unsigned short* wlo = wlds + NB * PITCH;
  int tid = threadIdx.x;
  int w = tid >> 6, l = tid & 63;
  int m = l & 15, kg = l >> 4;
  // bijective XCD-chunked swizzle (m204)
  int nwg = gridDim.x;
  int orig = blockIdx.x;
  int qd = nwg >> 3, rm = nwg & 7;
  int xcd = orig & 7, seq = orig >> 3;
  int wgid = (xcd < rm ? xcd * (qd + 1) : rm * (qd + 1) + (xcd - rm) * qd) + seq;
  int bc = wgid % NCB;
  int br = wgid / NCB;
  int row0 = br * 128;
  // stage FULL W-panel hi+lo once
  for (int i = tid; i < 2 * NB * KC; i += 256) {
    int mtx = i / (NB * KC);
    int j = i - mtx * (NB * KC);
    int n = j / KC, qq = j - n * KC;
    const unsigned short* src = mtx ? Wl : Wh;
    unsigned short* dst = mtx ? wlo : whi;
    *(us8*)&dst[n * PITCH + qq * 8] = *(const us8*)&src[(size_t)(bc * NB + n) * Kp + qq * 8];
  }
  // prefetch ALL A fragments into registers
  frag8 ah0[KS], al0[KS], ah1[KS], al1[KS];
  size_t arow0 = (size_t)(row0 + 32 * w + m) * Kp + kg * 8;
  size_t arow1 = arow0 + (size_t)16 * Kp;
#pragma unroll
  for (int kk = 0; kk < KS; ++kk) {
    ah0[kk] = *(const frag8*)(Ahp + arow0 + kk * 32);
    al0[kk] = *(const frag8*)(Alp + arow0 + kk * 32);
    ah1[kk] = *(const frag8*)(Ahp + arow1 + kk * 32);
    al1[kk] = *(const frag8*)(Alp + arow1 + kk * 32);
  }
  __syncthreads();

  f32x4 zero4 = {0.f, 0.f, 0.f, 0.f};
  f32x4 acc0[NT], acc1[NT];
#pragma unroll
  for (int t = 0; t < NT; ++t) { acc0[t] = zero4; acc1[t] = zero4; }

#pragma unroll
  for (int kk = 0; kk < KS; ++kk) {   // pure LDS+MFMA
#pragma unroll
    for (int t = 0; t < NT; ++t) {
      int n = t * 16 + m;
      int co = kk * 32 + kg * 8;
      frag8 bh = *(const frag8*)&whi[n * PITCH + co];
      frag8 bl = *(const frag8*)&wlo[n * PITCH + co];
      acc0[t] = __builtin_amdgcn_mfma_f32_16x16x32_bf16(ah0[kk], bh, acc0[t], 0, 0, 0);
      acc0[t] = __builtin_amdgcn_mfma_f32_16x16x32_bf16(ah0[kk], bl, acc0[t], 0, 0, 0);
      acc0[t] = __builtin_amdgcn_mfma_f32_16x16x32_bf16(al0[kk], bh, acc0[t], 0, 0, 0);
      acc1[t] = __builtin_amdgcn_mfma_f32_16x16x32_bf16(ah1[kk], bh, acc1[t], 0, 0, 0);
      acc1[t] = __builtin_amdgcn_mfma_f32_16x16x32_bf16(ah1[kk], bl, acc1[t], 0, 0, 0);
      acc1[t] = __builtin_amdgcn_mfma_f32_16x16x32_bf16(al1[kk], bh, acc1[t], 0, 0, 0);
    }
  }
  // epilogue: C/D layout (m89-verified): col = lane&15, row-in-frag = (lane>>4)*4 + reg
  if (!POOL) {
#pragma unroll
    for (int t = 0; t < NT; ++t) {
      int col = bc * NB + t * 16 + m;
      float b = (col < N) ? bias[col] : 0.f;
#pragma unroll
      for (int r = 0; r < 4; ++r) {
        int row = row0 + 32 * w + kg * 4 + r;
        float v0 = fmaxf(acc0[t][r] + b, 0.f);
        float v1 = fmaxf(acc1[t][r] + b, 0.f);
        C[(size_t)row * Np + col] = (col < N) ? v0 : 0.f;
        C[(size_t)(row + 16) * Np + col] = (col < N) ? v1 : 0.f;
      }
    }
  } else {
    int gA = batch[row0];  // block spans <=2 graphs (min graph size ~195 > 128)
    int rbase = row0 + 32 * w + kg * 4;
    int cls[8];  // 0 invalid, 1 graph A, 2 graph A+1
#pragma unroll
    for (int r = 0; r < 4; ++r) {
      int ra = rbase + r, rb = rbase + 16 + r;
      cls[r]     = (ra < M) ? ((batch[ra] == gA) ? 1 : 2) : 0;
      cls[4 + r] = (rb < M) ? ((batch[rb] == gA) ? 1 : 2) : 0;
    }
#pragma unroll
    for (int t = 0; t < NT; ++t) {
      int col = bc * NB + t * 16 + m;
      float b = (col < N) ? bias[col] : 0.f;
      float m0 = 0.f, m1 = 0.f;
#pragma unroll
      for (int r = 0; r < 4; ++r) {
        float v0 = fmaxf(acc0[t][r] + b, 0.f);
        float v1 = fmaxf(acc1[t][r] + b, 0.f);
        if (cls[r] == 1)     m0 = fmaxf(m0, v0); else if (cls[r] == 2)     m1 = fmaxf(m1, v0);
        if (cls[4 + r] == 1) m0 = fmaxf(m0, v1); else if (cls[4 + r] == 2) m1 = fmaxf(m1, v1);
      }
      m0 = fmaxf(m0, __shfl_xor(m0, 16)); m0 = fmaxf(m0, __shfl_xor(m0, 32));
      m1 = fmaxf(m1, __shfl_xor(m1, 16)); m1 = fmaxf(m1, __shfl_xor(m1, 32));
      if (l < 16 && col < N) {
        if (m0 > 0.f) atomicMax(&poolU[(size_t)gA * 320 + col], __float_as_uint(m0));
        if (m1 > 0.f) atomicMax(&poolU[(size_t)(gA + 1) * 320 + col], __float_as_uint(m1));
      }
    }
  }
}

// ---------------- head MFMA v2: conv-style. BM=64 (16 rows/wave), NB cols, optional K-split ----------------
template<int Kp, int Np, int NB, int KSPLIT, bool RELU, int OUTMODE, int SOUT, bool AU32>
__global__ __launch_bounds__(256) void k_hmm2(const unsigned short* __restrict__ Ahp,
                                              const unsigned short* __restrict__ Alp,
                                              const unsigned int* __restrict__ Au,
                                              const unsigned short* __restrict__ Wh,
                                              const unsigned short* __restrict__ Wl,
                                              const float* __restrict__ bias,
                                              float* __restrict__ partOrC,
                                              unsigned short* __restrict__ OutH,
                                              unsigned short* __restrict__ OutL) {
  constexpr int NCB = Np / NB;
  constexpr int NT = NB / 16;
  constexpr int KS = Kp / 32 / KSPLIT;
  constexpr int KSL = KS * 32;        // K-slice ushorts
  constexpr int CH8 = KSL / 8;
  constexpr int PITCH = KSL + 8;
  __shared__ unsigned short wlds[2 * NB * PITCH];
  unsigned short* whi = wlds;
  unsigned short* wlo = wlds + NB * PITCH;
  int tid = threadIdx.x;
  int w = tid >> 6, l = tid & 63;
  int m = l & 15, kg = l >> 4;
  int bc = blockIdx.x % NCB;
  int kc = (blockIdx.x / NCB) % KSPLIT;
  int br = blockIdx.x / (NCB * KSPLIT);
  int row0 = br * 64;
  int k0 = kc * KSL;
  // stage W K-slice hi+lo once
  for (int i = tid; i < 2 * NB * CH8; i += 256) {
    int mtx = i / (NB * CH8);
    int j = i - mtx * (NB * CH8);
    int n = j / CH8, q = j - n * CH8;
    const unsigned short* src = mtx ? Wl : Wh;
    unsigned short* dst = mtx ? wlo : whi;
    *(us8*)&dst[n * PITCH + q * 8] = *(const us8*)&src[(size_t)(bc * NB + n) * Kp + k0 + q * 8];
  }
  // prefetch A fragments
  frag8 ah[KS], al[KS];
  int arow = row0 + 16 * w + m;
  if (AU32) {
#pragma unroll
    for (int kk = 0; kk < KS; ++kk) {
      u32x8 uv = *(const u32x8*)(Au + (size_t)arow * Kp + k0 + kk * 32 + kg * 8);
      frag8 h8, l8;
#pragma unroll
      for (int j = 0; j < 8; ++j) {
        float v = __uint_as_float(uv[j]);
        unsigned short hh = bf16_rne(v);
        h8[j] = (short)hh;
        l8[j] = (short)bf16_rne(v - bf16_to_f(hh));
      }
      ah[kk] = h8; al[kk] = l8;
    }
  } else {
    size_t abase = (size_t)arow * Kp + k0 + kg * 8;
#pragma unroll
    for (int kk = 0; kk < KS; ++kk) {
      ah[kk] = *(const frag8*)(Ahp + abase + kk * 32);
      al[kk] = *(const frag8*)(Alp + abase + kk * 32);
    }
  }
  __syncthreads();

  f32x4 acc[NT];
#pragma unroll
  for (int t = 0; t < NT; ++t) acc[t] = (f32x4){0.f, 0.f, 0.f, 0.f};
#pragma unroll
  for (int kk = 0; kk < KS; ++kk) {
#pragma unroll
    for (int t = 0; t < NT; ++t) {
      int n = t * 16 + m;
      int co = kk * 32 + kg * 8;
      frag8 bh = *(const frag8*)&whi[n * PITCH + co];
      frag8 bl = *(const frag8*)&wlo[n * PITCH + co];
      acc[t] = __builtin_amdgcn_mfma_f32_16x16x32_bf16(ah[kk], bh, acc[t], 0, 0, 0);
      acc[t] = __builtin_amdgcn_mfma_f32_16x16x32_bf16(ah[kk], bl, acc[t], 0, 0, 0);
      acc[t] = __builtin_amdgcn_mfma_f32_16x16x32_bf16(al[kk], bh, acc[t], 0, 0, 0);
    }
  }
#pragma unroll
  for (int t = 0; t < NT; ++t) {
    int col = bc * NB + t * 16 + m;
#pragma unroll
    for (int r = 0; r < 4; ++r) {
      int row = row0 + 16 * w + kg * 4 + r;
      float v = acc[t][r];
      if (KSPLIT > 1) {
        partOrC[((size_t)(kc * 256) + row) * Np + col] = v;
      } else {
        v += bias[col];
        if (RELU) v = fmaxf(v, 0.f);
        if (OUTMODE == 0) {
          partOrC[(size_t)row * SOUT + col] = v;
        } else {
          unsigned short h = bf16_rne(v);
          OutH[(size_t)row * SOUT + col] = h;
          OutL[(size_t)row * SOUT + col] = bf16_rne(v - bf16_to_f(h));
        }
      }
    }
  }
}

// combine K-split partials: C = act(sum_kc part + bias); optional T/P insert (cols 128/129)
template<int Np, int KSPLIT, bool RELU, int OUTMODE, int SOUT, bool TP>
__global__ void k_comb(const float* __restrict__ part, const float* __restrict__ bias,
                       float* __restrict__ Cf, unsigned short* __restrict__ OutH,
                       unsigned short* __restrict__ OutL,
                       const float* __restrict__ T, const float* __restrict__ P) {
  int idx = blockIdx.x * 256 + threadIdx.x;   // over 256*Np
  int row = idx / Np, col = idx - row * Np;
  float s = bias[col];
#pragma unroll
  for (int kc = 0; kc < KSPLIT; ++kc) s += part[((size_t)(kc * 256) + row) * Np + col];
  if (RELU) s = fmaxf(s, 0.f);
  if (OUTMODE == 0) {
    Cf[(size_t)row * SOUT + col] = s;
  } else {
    unsigned short h = bf16_rne(s);
    OutH[(size_t)row * SOUT + col] = h;
    OutL[(size_t)row * SOUT + col] = bf16_rne(s - bf16_to_f(h));
  }
  if (TP && idx < 256) {
    int g = idx;
    float tv = T[g], pv = P[g];
    unsigned short th = bf16_rne(tv), ph = bf16_rne(pv);
    OutH[(size_t)g * SOUT + 128] = th;
    OutL[(size_t)g * SOUT + 128] = bf16_rne(tv - bf16_to_f(th));
    OutH[(size_t)g * SOUT + 129] = ph;
    OutL[(size_t)g * SOUT + 129] = bf16_rne(pv - bf16_to_f(ph));
  }
}

__global__ void k_final(const float* __restrict__ g4, const float* __restrict__ Wo,
                        const float* __restrict__ bo, float* __restrict__ out) {
  int g = blockIdx.x;
  int lane = threadIdx.x;  // 64
  float acc = 0.f;
#pragma unroll
  for (int u = 0; u < 8; ++u) {
    int k = lane + u * 64;
    acc += g4[(size_t)g * 512 + k] * Wo[k];
  }
  for (int s = 32; s > 0; s >>= 1) acc += __shfl_down(acc, s);
  if (lane == 0) out[g] = acc + bo[0];
}

// ---------------- launch ----------------
extern "C" void kernel_launch(void* const* d_in, const int* in_sizes, int n_in,
                              void* d_out, int out_size, void* d_ws, size_t ws_size,
                              hipStream_t stream) {
  const float* x   = (const float*)d_in[0];
  const int*   ei  = (const int*)d_in[1];
  const int*   bat = (const int*)d_in[2];
  const float* T   = (const float*)d_in[3];
  const float* P   = (const float*)d_in[4];
  const float* W1  = (const float*)d_in[5];
  const float* b1  = (const float*)d_in[6];
  const float* W2  = (const float*)d_in[7];
  const float* b2  = (const float*)d_in[8];
  const float* W3  = (const float*)d_in[9];
  const float* b3  = (const float*)d_in[10];
  const float* Wg1 = (const float*)d_in[11];
  const float* bg1 = (const float*)d_in[12];
  const float* Wg2 = (const float*)d_in[13];
  const float* bg2 = (const float*)d_in[14];
  const float* Wf1 = (const float*)d_in[15];
  const float* bf1 = (const float*)d_in[16];
  const float* Wf2 = (const float*)d_in[17];
  const float* bf2 = (const float*)d_in[18];
  const float* Wo  = (const float*)d_in[19];
  const float* bo  = (const float*)d_in[20];
  float* out = (float*)d_out;

  char* ws = (char*)d_ws;
  size_t off = 0;
  auto alloc = [&](size_t bytes) -> void* {
    void* p = ws + off;
    off = (off + bytes + 255) & ~(size_t)255;
    return p;
  };
  // ---- zero region (one memset): cnt + poolU + xcH + xcL ----
  char* zero_base = ws + off;
  int*           cnt   = (int*)alloc((size_t)NN * 4);
  unsigned int*  poolU = (unsigned int*)alloc((size_t)256 * 320 * 4);
  unsigned short* xcH  = (unsigned short*)alloc((size_t)256 * 160 * 2);
  unsigned short* xcL  = (unsigned short*)alloc((size_t)256 * 160 * 2);
  size_t zero_bytes = (size_t)((ws + off) - zero_base);
  // ---- conv buffers (overlays: x80/h1 at +0, h2 at +(NN+64)*80; h3 never materialized) ----
  float* Rbig    = (float*)alloc((size_t)(NN + 64) * 320 * 4);
  float* x80     = Rbig;
  float* h1      = Rbig;
  float* h2      = Rbig + (size_t)(NN + 64) * 80;
  unsigned short* aggH = (unsigned short*)alloc((size_t)(NN + 64) * 160 * 2);
  unsigned short* aggL = (unsigned short*)alloc((size_t)(NN + 64) * 160 * 2);
  unsigned short* wt1H = (unsigned short*)alloc((size_t)96 * 80 * 2);
  unsigned short* wt1L = (unsigned short*)alloc((size_t)96 * 80 * 2);
  unsigned short* wt2H = (unsigned short*)alloc((size_t)96 * 160 * 2);
  unsigned short* wt2L = (unsigned short*)alloc((size_t)96 * 160 * 2);
  unsigned short* wt3H = (unsigned short*)alloc((size_t)160 * 320 * 2);
  unsigned short* wt3L = (unsigned short*)alloc((size_t)160 * 320 * 2);
  int*   rowptr  = (int*)alloc((size_t)(NN + 1) * 4);
  int*   partial = (int*)alloc(64 * 4);
  int*   csr_src = (int*)alloc((size_t)NE * 4);
  float* csr_val = (float*)alloc((size_t)NE * 4);
  float* dinv    = (float*)alloc((size_t)NN * 4);
  // head weights hi/lo
  unsigned short* wg1H = (unsigned short*)alloc((size_t)1024 * 320 * 2);
  unsigned short* wg1L = (unsigned short*)alloc((size_t)1024 * 320 * 2);
  unsigned short* wg2H = (unsigned short*)alloc((size_t)128 * 1024 * 2);
  unsigned short* wg2L = (unsigned short*)alloc((size_t)128 * 1024 * 2);
  unsigned short* wf1H = (unsigned short*)alloc((size_t)1024 * 160 * 2);
  unsigned short* wf1L = (unsigned short*)alloc((size_t)1024 * 160 * 2);
  unsigned short* wf2H = (unsigned short*)alloc((size_t)512 * 1024 * 2);
  unsigned short* wf2L = (unsigned short*)alloc((size_t)512 * 1024 * 2);
  // head activations hi/lo
  unsigned short* g1H = (unsigned short*)alloc((size_t)256 * 1024 * 2);
  unsigned short* g1L = (unsigned short*)alloc((size_t)256 * 1024 * 2);
  unsigned short* g3H = (unsigned short*)alloc((size_t)256 * 1024 * 2);
  unsigned short* g3L = (unsigned short*)alloc((size_t)256 * 1024 * 2);
  float* g4      = (float*)alloc((size_t)256 * 512 * 4);
  float* hpart   = (float*)alloc((size_t)8 * 256 * 512 * 4);  // K-split partials
  (void)ws_size; (void)in_sizes; (void)n_in; (void)out_size;

  const int* srcp = ei;        // edge_index[0]
  const int* dstp = ei + NE;   // edge_index[1]

  // single zero-init (cnt histogram; poolU >=0 maxes; xc pad cols)
  hipMemsetAsync(zero_base, 0, zero_bytes, stream);

  // prep: edge count + x-pad + all weight decompositions (concurrent)
  k_prep<<<PREP_BLOCKS, 256, 0, stream>>>(dstp, cnt, x, x80,
                                          W1, wt1H, wt1L, W2, wt2H, wt2L, W3, wt3H, wt3L,
                                          Wg1, wg1H, wg1L, Wg2, wg2H, wg2L,
                                          Wf1, wf1H, wf1L, Wf2, wf2H, wf2L);
  // CSR build
  int nb = (NN + 1023) / 1024;
  k_scan_partial<<<nb, 1024, 0, stream>>>(cnt, partial, dinv, NN);
  k_scan_final<<<nb, 1024, 0, stream>>>(cnt, partial, rowptr, NN);
  k_fill<<<(NE + 255) / 256, 256, 0, stream>>>(srcp, dstp, rowptr, cnt, dinv, csr_src, csr_val, NE);

  const int aggBlocks = (NN * 64) / 256;      // one wave per node (one-shot; measured optimum)
  const int mmRows128 = (NN + 127) / 128;     // 391 (BM=128)

  // conv1: agg(x80) -> Kp=96; h1 = relu(agg@W1 + b1), Np=80, NB=80
  k_agg_dec8<10, 12, 6><<<aggBlocks, 256, 0, stream>>>(x80, rowptr, csr_src, csr_val, dinv, aggH, aggL, NN);
  k_mm_mfma<96, 80, 80, false><<<mmRows128, 256, 0, stream>>>(
      aggH, aggL, wt1H, wt1L, b1, h1, nullptr, nullptr, 78, NN);
  // conv2: NB=80, NCB=2
  k_agg_dec8<10, 12, 6><<<aggBlocks, 256, 0, stream>>>(h1, rowptr, csr_src, csr_val, dinv, aggH, aggL, NN);
  k_mm_mfma<96, 160, 80, false><<<mmRows128 * 2, 256, 0, stream>>>(
      aggH, aggL, wt2H, wt2L, b2, h2, nullptr, nullptr, 156, NN);
  // conv3: fused pool epilogue (no h3 materialization), NB=80, NCB=4
  k_agg_dec8<20, 20, 3><<<aggBlocks, 256, 0, stream>>>(h2, rowptr, csr_src, csr_val, dinv, aggH, aggL, NN);
  k_mm_mfma<160, 320, 80, true><<<mmRows128 * 4, 256, 0, stream>>>(
      aggH, aggL, wt3H, wt3L, b3, nullptr, bat, poolU, 312, NN);

  // head L1: g1 = relu(pool @ Wg1 + bg1)  [256,320]x[320,1024]; A from poolU (u32 decompose)
  k_hmm2<320, 1024, 32, 1, true, 1, 1024, true><<<4 * 32, 256, 0, stream>>>(
      nullptr, nullptr, poolU, wg1H, wg1L, bg1, nullptr, g1H, g1L);
  // head L2: g2 = g1 @ Wg2 + bg2   [256,1024]x[1024,128], 8-way K-split
  k_hmm2<1024, 128, 32, 8, false, 0, 0, false><<<4 * 4 * 8, 256, 0, stream>>>(
      g1H, g1L, nullptr, wg2H, wg2L, nullptr, hpart, nullptr, nullptr);
  k_comb<128, 8, false, 1, 160, true><<<128, 256, 0, stream>>>(hpart, bg2, nullptr, xcH, xcL, T, P);
  // head L3: g3 = relu(xc @ Wf1 + bf1)   [256,160]x[160,1024]
  k_hmm2<160, 1024, 32, 1, true, 1, 1024, false><<<4 * 32, 256, 0, stream>>>(
      xcH, xcL, nullptr, wf1H, wf1L, bf1, nullptr, g3H, g3L);
  // head L4: g4 = relu(g3 @ Wf2 + bf2)   [256,1024]x[1024,512], 8-way K-split
  k_hmm2<1024, 512, 32, 8, false, 0, 0, false><<<4 * 16 * 8, 256, 0, stream>>>(
      g3H, g3L, nullptr, wf2H, wf2L, nullptr, hpart, nullptr, nullptr);
  k_comb<512, 8, true, 0, 512, false><<<512, 256, 0, stream>>>(hpart, bf2, g4, nullptr, nullptr, nullptr, nullptr);
  // final: out = g4 @ Wo + bo
  k_final<<<NG, 64, 0, stream>>>(g4, Wo, bo, out);
}